// Round 1
// baseline (101.367 us; speedup 1.0000x reference)
//
#include <hip/hip_runtime.h>
#include <math.h>

// Problem constants (B=16, H=512, W=512, fp32 in/out)
#define BB 16
#define HH 512
#define WW 512
#define NPIX (BB*HH*WW)   // 4194304
#define NROWS (BB*HH)     // 8192
#define NCOLS (BB*WW)     // 8192
#define PADK 512          // pad for pass-2 LDS row (worst-case scan reach)

// ---------------------------------------------------------------------------
// Kernel 1: vertical pass. One thread per (b, w) column. Forward sweep writes
// the forward run-distance into dv2; backward sweep combines and squares.
// Result: dv2[b,h,w] = (min |h - h_fg|)^2 within the column, exactly as the
// reference's first min-plus pass; exactly 1e12f for empty columns.
// ---------------------------------------------------------------------------
__global__ __launch_bounds__(64) void edt_cols_kernel(
    const float* __restrict__ tg, float* __restrict__ dv2) {
  int tid = blockIdx.x * 64 + threadIdx.x;
  if (tid >= NCOLS) return;
  int b = tid / WW, w = tid - b * WW;
  size_t base = (size_t)b * HH * WW + w;

  float d = 1023.f;
  #pragma unroll 8
  for (int i = 0; i < HH; ++i) {
    float t = tg[base + (size_t)i * WW];
    d = (t > 0.f) ? 0.f : fminf(d + 1.f, 1023.f);
    dv2[base + (size_t)i * WW] = d;
  }
  d = 1023.f;
  #pragma unroll 8
  for (int i = HH - 1; i >= 0; --i) {
    float f = dv2[base + (size_t)i * WW];   // forward distance (0 iff fg pixel)
    d = (f == 0.f) ? 0.f : fminf(d + 1.f, 1023.f);
    float m = fminf(d, f);
    dv2[base + (size_t)i * WW] = (m >= 512.f) ? 1e12f : m * m;
  }
}

// ---------------------------------------------------------------------------
// Kernel 2: horizontal pass + fused loss terms. One block per (b, h) row.
// best(i) = min_j dv2[j] + (i-j)^2 via outward scan with early exit
// (valid since dv2 >= 0 so candidates at offset o are >= o^2).
// Then p = sigmoid(logit), weight = 1-exp(-sqrt(best)/50) (0 if no fg),
// accumulate {sum p, sum t, sum p*t, sum w*p*(1-t)} -> per-block partials.
// ---------------------------------------------------------------------------
__global__ __launch_bounds__(256) void edt_rows_loss_kernel(
    const float* __restrict__ logits, const float* __restrict__ tg,
    const float* __restrict__ dv2, float* __restrict__ partials) {
  __shared__ float s[PADK + WW + PADK];
  __shared__ float wsum[4][4];

  int row = blockIdx.x;           // b*HH + h
  size_t rowbase = (size_t)row * WW;
  int tid = threadIdx.x;

  // pads (never allowed to win the min): 2 writes each side per thread
  s[tid] = 3e12f; s[tid + 256] = 3e12f;
  s[PADK + WW + tid] = 3e12f; s[PADK + WW + 256 + tid] = 3e12f;
  // row data
  s[PADK + tid] = dv2[rowbase + tid];
  s[PADK + 256 + tid] = dv2[rowbase + 256 + tid];
  __syncthreads();

  float acc_p = 0.f, acc_t = 0.f, acc_pt = 0.f, acc_pen = 0.f;

  #pragma unroll
  for (int k = 0; k < 2; ++k) {
    int i = tid + k * 256;
    float best = s[PADK + i];
    for (int o = 1; o < WW; ++o) {
      float oo = (float)(o * o);
      if (oo >= best) break;    // no farther candidate can beat best
      float cand = fminf(s[PADK + i - o], s[PADK + i + o]) + oo;
      best = fminf(best, cand);
    }
    float x = logits[rowbase + i];
    float p = 1.f / (1.f + expf(-x));
    float t = tg[rowbase + i];
    // empty sample => best ~ 1e12 => reference forces weight 0 (has_fg)
    float wgt = (best > 1e9f) ? 0.f : (1.f - expf(-sqrtf(best) * (1.f / 50.f)));
    acc_p  += p;
    acc_t  += t;
    acc_pt += p * t;
    acc_pen += wgt * p * (1.f - t);
  }

  // wave(64) shuffle reduce, then across the 4 waves via LDS
  #pragma unroll
  for (int off = 32; off; off >>= 1) {
    acc_p  += __shfl_down(acc_p,  off);
    acc_t  += __shfl_down(acc_t,  off);
    acc_pt += __shfl_down(acc_pt, off);
    acc_pen += __shfl_down(acc_pen, off);
  }
  int wave = tid >> 6, lane = tid & 63;
  if (lane == 0) {
    wsum[wave][0] = acc_p; wsum[wave][1] = acc_t;
    wsum[wave][2] = acc_pt; wsum[wave][3] = acc_pen;
  }
  __syncthreads();
  if (tid == 0) {
    float r0 = 0.f, r1 = 0.f, r2 = 0.f, r3 = 0.f;
    #pragma unroll
    for (int wv = 0; wv < 4; ++wv) {
      r0 += wsum[wv][0]; r1 += wsum[wv][1];
      r2 += wsum[wv][2]; r3 += wsum[wv][3];
    }
    partials[0 * NROWS + row] = r0;
    partials[1 * NROWS + row] = r1;
    partials[2 * NROWS + row] = r2;
    partials[3 * NROWS + row] = r3;
  }
}

// ---------------------------------------------------------------------------
// Kernel 3: deterministic final reduce of 8192x4 partials + scalar loss.
// ---------------------------------------------------------------------------
__global__ __launch_bounds__(256) void finalize_kernel(
    const float* __restrict__ partials, float* __restrict__ out) {
  __shared__ float wsum[4][4];
  int tid = threadIdx.x;
  float a0 = 0.f, a1 = 0.f, a2 = 0.f, a3 = 0.f;
  for (int k = tid; k < NROWS; k += 256) {
    a0 += partials[0 * NROWS + k];
    a1 += partials[1 * NROWS + k];
    a2 += partials[2 * NROWS + k];
    a3 += partials[3 * NROWS + k];
  }
  #pragma unroll
  for (int off = 32; off; off >>= 1) {
    a0 += __shfl_down(a0, off);
    a1 += __shfl_down(a1, off);
    a2 += __shfl_down(a2, off);
    a3 += __shfl_down(a3, off);
  }
  int wave = tid >> 6, lane = tid & 63;
  if (lane == 0) {
    wsum[wave][0] = a0; wsum[wave][1] = a1;
    wsum[wave][2] = a2; wsum[wave][3] = a3;
  }
  __syncthreads();
  if (tid == 0) {
    float sp = 0.f, st = 0.f, inter = 0.f, pen = 0.f;
    #pragma unroll
    for (int wv = 0; wv < 4; ++wv) {
      sp += wsum[wv][0]; st += wsum[wv][1];
      inter += wsum[wv][2]; pen += wsum[wv][3];
    }
    float uni = sp + st - inter;
    float iou_loss = 1.f - (inter + 1e-6f) / (uni + 1e-6f);
    float penalty = pen / (float)NPIX;
    out[0] = iou_loss + 0.5f * penalty;
  }
}

extern "C" void kernel_launch(void* const* d_in, const int* in_sizes, int n_in,
                              void* d_out, int out_size, void* d_ws, size_t ws_size,
                              hipStream_t stream) {
  const float* logits = (const float*)d_in[0];
  const float* tg     = (const float*)d_in[1];
  float* dv2      = (float*)d_ws;            // NPIX floats (16.7 MB)
  float* partials = dv2 + NPIX;              // 4 * NROWS floats (128 KB)
  float* out      = (float*)d_out;

  hipLaunchKernelGGL(edt_cols_kernel, dim3(NCOLS / 64), dim3(64), 0, stream,
                     tg, dv2);
  hipLaunchKernelGGL(edt_rows_loss_kernel, dim3(NROWS), dim3(256), 0, stream,
                     logits, tg, dv2, partials);
  hipLaunchKernelGGL(finalize_kernel, dim3(1), dim3(256), 0, stream,
                     partials, out);
}

// Round 2
// 89.623 us; speedup vs baseline: 1.1310x; 1.1310x over previous
//
#include <hip/hip_runtime.h>
#include <math.h>

// Problem constants (B=16, H=512, W=512, fp32 in/out)
#define BB 16
#define HH 512
#define WW 512
#define NPIX (BB*HH*WW)   // 4194304
#define NROWS (BB*HH)     // 8192
#define NWORDS 16         // 512 rows / 32 bits
#define PADK 512          // pad for horizontal LDS row (worst-case scan reach)

// ---------------------------------------------------------------------------
// Kernel A: build column bitmasks. mask[b][k][w] bit r set iff
// targets[b, 32k+r, w] > 0. No atomics: each thread owns one word.
// Reads tg exactly once, coalesced (wave lanes = 64 consecutive w, same row).
// ---------------------------------------------------------------------------
__global__ __launch_bounds__(256) void build_mask_kernel(
    const float* __restrict__ tg, unsigned int* __restrict__ mask) {
  int wt = blockIdx.x & 7;          // 8 column tiles of 64
  int kg = (blockIdx.x >> 3) & 3;   // 4 word groups of 4
  int b  = blockIdx.x >> 5;
  int w  = (wt << 6) + (threadIdx.x & 63);
  int k  = (kg << 2) + (threadIdx.x >> 6);
  const float* p = tg + ((size_t)(b * HH + (k << 5))) * WW + w;
  unsigned int word = 0;
  #pragma unroll
  for (int r = 0; r < 32; ++r) {
    word |= (p[(size_t)r * WW] > 0.f ? 1u : 0u) << r;
  }
  mask[(b * NWORDS + k) * WW + w] = word;
}

// ---------------------------------------------------------------------------
// Kernel B: fused vertical EDT (from bitmask) + horizontal min-plus + loss.
// One block per (b, h) row. Each thread handles 2 columns.
// Vertical: nearest set bit in the column's 16-word mask, scanning outward
// from the row's word with a distance-bound early exit.
// Horizontal: best(i) = min_j dv2[j] + (i-j)^2 via outward scan w/ early exit.
// All finite values are exact small ints in fp32 -> bit-identical to ref.
// ---------------------------------------------------------------------------
__global__ __launch_bounds__(256) void rows_loss_kernel(
    const float* __restrict__ logits, const unsigned int* __restrict__ mask,
    float* __restrict__ partials) {
  __shared__ float s[PADK + WW + PADK];
  __shared__ float wsum[4][4];

  int row = blockIdx.x;             // b*HH + h
  int b = row >> 9, i = row & 511;  // h index within image
  size_t rowbase = (size_t)row * WW;
  int tid = threadIdx.x;

  // pads (never allowed to win the min)
  s[tid] = 3e12f; s[tid + 256] = 3e12f;
  s[PADK + WW + tid] = 3e12f; s[PADK + WW + 256 + tid] = 3e12f;

  int k0 = i >> 5, pos = i & 31;
  float tval[2];

  #pragma unroll
  for (int k2 = 0; k2 < 2; ++k2) {
    int w = tid + (k2 << 8);
    const unsigned int* mcol = mask + (b * NWORDS) * WW + w;
    unsigned int m0 = mcol[k0 * WW];
    tval[k2] = (float)((m0 >> pos) & 1u);
    int best = 1023;
    unsigned int lowm = m0 & ((2u << pos) - 1u);  // bits 0..pos
    unsigned int upm  = m0 ^ lowm;                // bits pos+1..31
    if (lowm) best = pos - (31 - __builtin_clz(lowm));
    if (upm)  best = min(best, (int)__builtin_ctz(upm) - pos);
    #pragma unroll 1
    for (int d = 1; d < 16; ++d) {
      int lodist = (d << 5) - 31 + pos;  // min possible dist from word k0-d
      int hidist = (d << 5) - pos;       // min possible dist from word k0+d
      if (lodist >= best && hidist >= best) break;
      int kl = k0 - d, kh = k0 + d;
      if (kl >= 0 && lodist < best) {
        unsigned int m = mcol[kl * WW];
        if (m) best = min(best, i - ((kl << 5) + 31 - __builtin_clz(m)));
      }
      if (kh < 16 && hidist < best) {
        unsigned int m = mcol[kh * WW];
        if (m) best = min(best, (kh << 5) + (int)__builtin_ctz(m) - i);
      }
    }
    // empty column -> best stays 1023 -> 1e12, matching the reference exactly
    s[PADK + w] = (best > 511) ? 1e12f : (float)(best * best);
  }
  __syncthreads();

  float acc_p = 0.f, acc_t = 0.f, acc_pt = 0.f, acc_pen = 0.f;

  #pragma unroll
  for (int k2 = 0; k2 < 2; ++k2) {
    int w = tid + (k2 << 8);
    float best = s[PADK + w];
    for (int o = 1; o < WW; ++o) {
      float oo = (float)(o * o);
      if (oo >= best) break;  // dv2 >= 0 so farther candidates can't win
      float cand = fminf(s[PADK + w - o], s[PADK + w + o]) + oo;
      best = fminf(best, cand);
    }
    float x = logits[rowbase + w];
    float p = 1.f / (1.f + expf(-x));
    float t = tval[k2];
    // empty sample => best ~ 1e12 => reference forces weight 0 (has_fg)
    float wgt = (best > 1e9f) ? 0.f : (1.f - expf(-sqrtf(best) * (1.f / 50.f)));
    acc_p  += p;
    acc_t  += t;
    acc_pt += p * t;
    acc_pen += wgt * p * (1.f - t);
  }

  // wave(64) shuffle reduce, then across the 4 waves via LDS
  #pragma unroll
  for (int off = 32; off; off >>= 1) {
    acc_p  += __shfl_down(acc_p,  off);
    acc_t  += __shfl_down(acc_t,  off);
    acc_pt += __shfl_down(acc_pt, off);
    acc_pen += __shfl_down(acc_pen, off);
  }
  int wave = tid >> 6, lane = tid & 63;
  if (lane == 0) {
    wsum[wave][0] = acc_p; wsum[wave][1] = acc_t;
    wsum[wave][2] = acc_pt; wsum[wave][3] = acc_pen;
  }
  __syncthreads();
  if (tid == 0) {
    float r0 = 0.f, r1 = 0.f, r2 = 0.f, r3 = 0.f;
    #pragma unroll
    for (int wv = 0; wv < 4; ++wv) {
      r0 += wsum[wv][0]; r1 += wsum[wv][1];
      r2 += wsum[wv][2]; r3 += wsum[wv][3];
    }
    partials[0 * NROWS + row] = r0;
    partials[1 * NROWS + row] = r1;
    partials[2 * NROWS + row] = r2;
    partials[3 * NROWS + row] = r3;
  }
}

// ---------------------------------------------------------------------------
// Kernel C: deterministic final reduce of 8192x4 partials + scalar loss.
// ---------------------------------------------------------------------------
__global__ __launch_bounds__(256) void finalize_kernel(
    const float* __restrict__ partials, float* __restrict__ out) {
  __shared__ float wsum[4][4];
  int tid = threadIdx.x;
  float a0 = 0.f, a1 = 0.f, a2 = 0.f, a3 = 0.f;
  for (int k = tid; k < NROWS; k += 256) {
    a0 += partials[0 * NROWS + k];
    a1 += partials[1 * NROWS + k];
    a2 += partials[2 * NROWS + k];
    a3 += partials[3 * NROWS + k];
  }
  #pragma unroll
  for (int off = 32; off; off >>= 1) {
    a0 += __shfl_down(a0, off);
    a1 += __shfl_down(a1, off);
    a2 += __shfl_down(a2, off);
    a3 += __shfl_down(a3, off);
  }
  int wave = tid >> 6, lane = tid & 63;
  if (lane == 0) {
    wsum[wave][0] = a0; wsum[wave][1] = a1;
    wsum[wave][2] = a2; wsum[wave][3] = a3;
  }
  __syncthreads();
  if (tid == 0) {
    float sp = 0.f, st = 0.f, inter = 0.f, pen = 0.f;
    #pragma unroll
    for (int wv = 0; wv < 4; ++wv) {
      sp += wsum[wv][0]; st += wsum[wv][1];
      inter += wsum[wv][2]; pen += wsum[wv][3];
    }
    float uni = sp + st - inter;
    float iou_loss = 1.f - (inter + 1e-6f) / (uni + 1e-6f);
    float penalty = pen / (float)NPIX;
    out[0] = iou_loss + 0.5f * penalty;
  }
}

extern "C" void kernel_launch(void* const* d_in, const int* in_sizes, int n_in,
                              void* d_out, int out_size, void* d_ws, size_t ws_size,
                              hipStream_t stream) {
  const float* logits = (const float*)d_in[0];
  const float* tg     = (const float*)d_in[1];
  unsigned int* mask  = (unsigned int*)d_ws;              // 16*16*512 words = 512 KB
  float* partials     = (float*)d_ws + BB * NWORDS * WW;  // 4 * NROWS floats
  float* out          = (float*)d_out;

  hipLaunchKernelGGL(build_mask_kernel, dim3(BB * 4 * (WW / 64)), dim3(256), 0,
                     stream, tg, mask);
  hipLaunchKernelGGL(rows_loss_kernel, dim3(NROWS), dim3(256), 0, stream,
                     logits, mask, partials);
  hipLaunchKernelGGL(finalize_kernel, dim3(1), dim3(256), 0, stream,
                     partials, out);
}

// Round 3
// 58.906 us; speedup vs baseline: 1.7208x; 1.5215x over previous
//
#include <hip/hip_runtime.h>
#include <math.h>

// Problem constants (B=16, H=512, W=512, fp32 in/out)
#define BB 16
#define HH 512
#define WW 512
#define NPIX (BB*HH*WW)   // 4194304
#define NROWS (BB*HH)     // 8192
#define NWORDS 16         // 512 rows / 32 bits
#define PADK 512          // pad for horizontal LDS row (worst-case scan reach)

// ---------------------------------------------------------------------------
// Kernel A: build column bitmasks. mask[b][k][w] bit r set iff
// targets[b, 32k+r, w] > 0. No atomics: each thread owns one word.
// ---------------------------------------------------------------------------
__global__ __launch_bounds__(256) void build_mask_kernel(
    const float* __restrict__ tg, unsigned int* __restrict__ mask) {
  int wt = blockIdx.x & 7;          // 8 column tiles of 64
  int kg = (blockIdx.x >> 3) & 3;   // 4 word groups of 4
  int b  = blockIdx.x >> 5;
  int w  = (wt << 6) + (threadIdx.x & 63);
  int k  = (kg << 2) + (threadIdx.x >> 6);
  const float* p = tg + ((size_t)(b * HH + (k << 5))) * WW + w;
  unsigned int word = 0;
  #pragma unroll
  for (int r = 0; r < 32; ++r) {
    word |= (p[(size_t)r * WW] > 0.f ? 1u : 0u) << r;
  }
  mask[(b * NWORDS + k) * WW + w] = word;
}

// ---------------------------------------------------------------------------
// Kernel B: fused vertical EDT (branch-free 16-word bitmask scan) +
// horizontal min-plus (chunked, wave-uniform early exit) + loss terms.
// One block per (b, h) row; each thread handles 2 columns.
// All finite values are exact small ints in fp32 -> bit-identical to ref.
// ---------------------------------------------------------------------------
__global__ __launch_bounds__(256) void rows_loss_kernel(
    const float* __restrict__ logits, const unsigned int* __restrict__ mask,
    float* __restrict__ partials) {
  __shared__ float s[PADK + WW + PADK];
  __shared__ float wsum[4][4];

  int row = blockIdx.x;             // b*HH + h
  int b = row >> 9, i = row & 511;  // h index within image
  size_t rowbase = (size_t)row * WW;
  int tid = threadIdx.x;

  // pads (never allowed to win the min)
  s[tid] = 3e12f; s[tid + 256] = 3e12f;
  s[PADK + WW + tid] = 3e12f; s[PADK + WW + 256 + tid] = 3e12f;

  int k0 = i >> 5, pos = i & 31;    // block-uniform
  unsigned int pmask_lo = (1u << pos) - 1u;       // bits < pos
  unsigned int pmask_le = pmask_lo | (1u << pos); // bits <= pos
  float tval[2];

  #pragma unroll
  for (int k2 = 0; k2 < 2; ++k2) {
    int w = tid + (k2 << 8);
    const unsigned int* mcol = mask + (b * NWORDS) * WW + w;
    int up = 1 << 20;     // nearest set-bit abs position >= i
    int dn = -(1 << 20);  // nearest set-bit abs position <= i
    #pragma unroll
    for (int k = 0; k < 16; ++k) {
      unsigned int m = mcol[k * WW];   // 16 independent coalesced L2 loads
      unsigned int um = (k > k0) ? m : ((k == k0) ? (m & ~pmask_lo) : 0u);
      unsigned int dm = (k < k0) ? m : ((k == k0) ? (m & pmask_le) : 0u);
      int ucand = um ? ((k << 5) + (int)__builtin_ctz(um)) : (1 << 20);
      int dcand = dm ? ((k << 5) + 31 - (int)__builtin_clz(dm)) : -(1 << 20);
      up = min(up, ucand);
      dn = max(dn, dcand);
    }
    int bestv = min(up - i, i - dn);
    tval[k2] = (up == i) ? 1.f : 0.f;   // bit i set iff nearest-up is i itself
    s[PADK + w] = (bestv > 511) ? 1e12f : (float)(bestv * bestv);
  }
  __syncthreads();

  float acc_p = 0.f, acc_t = 0.f, acc_pt = 0.f, acc_pen = 0.f;

  #pragma unroll
  for (int k2 = 0; k2 < 2; ++k2) {
    int w = tid + (k2 << 8);
    float x = logits[rowbase + w];     // issue early, consumed after scan
    float best = s[PADK + w];
    for (int o0 = 1; o0 < WW; o0 += 8) {
      if (__all((float)(o0 * o0) >= best)) break;  // wave-uniform exit
      #pragma unroll
      for (int u = 0; u < 8; ++u) {
        int o = o0 + u;
        float cand = fminf(s[PADK + w - o], s[PADK + w + o]) + (float)(o * o);
        best = fminf(best, cand);      // unconditional: losers can't lower best
      }
    }
    float p = 1.f / (1.f + expf(-x));
    float t = tval[k2];
    // empty sample => best ~ 1e12 => reference forces weight 0 (has_fg)
    float wgt = (best > 1e9f) ? 0.f : (1.f - expf(-sqrtf(best) * (1.f / 50.f)));
    acc_p  += p;
    acc_t  += t;
    acc_pt += p * t;
    acc_pen += wgt * p * (1.f - t);
  }

  // wave(64) shuffle reduce, then across the 4 waves via LDS
  #pragma unroll
  for (int off = 32; off; off >>= 1) {
    acc_p  += __shfl_down(acc_p,  off);
    acc_t  += __shfl_down(acc_t,  off);
    acc_pt += __shfl_down(acc_pt, off);
    acc_pen += __shfl_down(acc_pen, off);
  }
  int wave = tid >> 6, lane = tid & 63;
  if (lane == 0) {
    wsum[wave][0] = acc_p; wsum[wave][1] = acc_t;
    wsum[wave][2] = acc_pt; wsum[wave][3] = acc_pen;
  }
  __syncthreads();
  if (tid == 0) {
    float r0 = 0.f, r1 = 0.f, r2 = 0.f, r3 = 0.f;
    #pragma unroll
    for (int wv = 0; wv < 4; ++wv) {
      r0 += wsum[wv][0]; r1 += wsum[wv][1];
      r2 += wsum[wv][2]; r3 += wsum[wv][3];
    }
    partials[0 * NROWS + row] = r0;
    partials[1 * NROWS + row] = r1;
    partials[2 * NROWS + row] = r2;
    partials[3 * NROWS + row] = r3;
  }
}

// ---------------------------------------------------------------------------
// Kernel C: deterministic final reduce of 8192x4 partials + scalar loss.
// ---------------------------------------------------------------------------
__global__ __launch_bounds__(256) void finalize_kernel(
    const float* __restrict__ partials, float* __restrict__ out) {
  __shared__ float wsum[4][4];
  int tid = threadIdx.x;
  float a0 = 0.f, a1 = 0.f, a2 = 0.f, a3 = 0.f;
  for (int k = tid; k < NROWS; k += 256) {
    a0 += partials[0 * NROWS + k];
    a1 += partials[1 * NROWS + k];
    a2 += partials[2 * NROWS + k];
    a3 += partials[3 * NROWS + k];
  }
  #pragma unroll
  for (int off = 32; off; off >>= 1) {
    a0 += __shfl_down(a0, off);
    a1 += __shfl_down(a1, off);
    a2 += __shfl_down(a2, off);
    a3 += __shfl_down(a3, off);
  }
  int wave = tid >> 6, lane = tid & 63;
  if (lane == 0) {
    wsum[wave][0] = a0; wsum[wave][1] = a1;
    wsum[wave][2] = a2; wsum[wave][3] = a3;
  }
  __syncthreads();
  if (tid == 0) {
    float sp = 0.f, st = 0.f, inter = 0.f, pen = 0.f;
    #pragma unroll
    for (int wv = 0; wv < 4; ++wv) {
      sp += wsum[wv][0]; st += wsum[wv][1];
      inter += wsum[wv][2]; pen += wsum[wv][3];
    }
    float uni = sp + st - inter;
    float iou_loss = 1.f - (inter + 1e-6f) / (uni + 1e-6f);
    float penalty = pen / (float)NPIX;
    out[0] = iou_loss + 0.5f * penalty;
  }
}

extern "C" void kernel_launch(void* const* d_in, const int* in_sizes, int n_in,
                              void* d_out, int out_size, void* d_ws, size_t ws_size,
                              hipStream_t stream) {
  const float* logits = (const float*)d_in[0];
  const float* tg     = (const float*)d_in[1];
  unsigned int* mask  = (unsigned int*)d_ws;              // 16*16*512 words = 512 KB
  float* partials     = (float*)d_ws + BB * NWORDS * WW;  // 4 * NROWS floats
  float* out          = (float*)d_out;

  hipLaunchKernelGGL(build_mask_kernel, dim3(BB * 4 * (WW / 64)), dim3(256), 0,
                     stream, tg, mask);
  hipLaunchKernelGGL(rows_loss_kernel, dim3(NROWS), dim3(256), 0, stream,
                     logits, mask, partials);
  hipLaunchKernelGGL(finalize_kernel, dim3(1), dim3(256), 0, stream,
                     partials, out);
}

// Round 4
// 41.397 us; speedup vs baseline: 2.4486x; 1.4229x over previous
//
#include <hip/hip_runtime.h>
#include <math.h>

// Problem constants (B=16, H=512, W=512, fp32 in/out)
#define BB 16
#define HH 512
#define WW 512
#define NPIX (BB*HH*WW)   // 4194304
#define NROWS (BB*HH)     // 8192
#define NWORDS 16         // 512 rows / 32 bits
#define PADK 512          // pad for horizontal LDS row (worst-case scan reach)

// ---------------------------------------------------------------------------
// Kernel A: build column bitmasks AND per-column nearest-set-bit prefix
// tables. Block = (b, 64-column tile); 256 threads build 16 words x 64 cols
// in LDS (coalesced tg reads, each thread owns 4 words), then 128 threads
// aggregate:
//   un[b][k][w] = abs pos of first set bit >= 32k   (slot 16 = sentinel 16000)
//   dn[b][k+1][w] = abs pos of last set bit <= 32k+31 (slot 0 = sentinel -16000)
// ---------------------------------------------------------------------------
__global__ __launch_bounds__(256) void build_kernel(
    const float* __restrict__ tg, unsigned int* __restrict__ mask,
    short* __restrict__ un_s, short* __restrict__ dn_s) {
  __shared__ unsigned int smask[NWORDS][64];
  int wt = blockIdx.x & 7;
  int b  = blockIdx.x >> 3;
  int lane = threadIdx.x & 63;
  int kq = threadIdx.x >> 6;      // 0..3
  int w = (wt << 6) + lane;
  #pragma unroll
  for (int kk = 0; kk < 4; ++kk) {
    int k = (kq << 2) + kk;
    const float* p = tg + ((size_t)(b * HH + (k << 5))) * WW + w;
    unsigned int word = 0;
    #pragma unroll
    for (int r = 0; r < 32; ++r)
      word |= (p[(size_t)r * WW] > 0.f ? 1u : 0u) << r;
    smask[k][lane] = word;
    mask[(b * NWORDS + k) * WW + w] = word;
  }
  __syncthreads();
  int t = threadIdx.x;
  if (t < 64) {                  // suffix scan: first set bit >= 32k
    int wcol = (wt << 6) + t;
    int cur = 16000;
    un_s[(b * 17 + 16) * WW + wcol] = (short)cur;
    for (int k = NWORDS - 1; k >= 0; --k) {
      unsigned int m = smask[k][t];
      if (m) cur = (k << 5) + (int)__builtin_ctz(m);
      un_s[(b * 17 + k) * WW + wcol] = (short)cur;
    }
  } else if (t < 128) {          // prefix scan: last set bit <= 32k+31
    int tt = t - 64;
    int wcol = (wt << 6) + tt;
    int cur = -16000;
    dn_s[(b * 17 + 0) * WW + wcol] = (short)cur;
    for (int k = 0; k < NWORDS; ++k) {
      unsigned int m = smask[k][tt];
      if (m) cur = (k << 5) + 31 - (int)__builtin_clz(m);
      dn_s[(b * 17 + k + 1) * WW + wcol] = (short)cur;
    }
  }
}

// ---------------------------------------------------------------------------
// Kernel B: fused vertical EDT (O(1) per pixel from precomputed tables) +
// horizontal min-plus (chunked, wave-uniform early exit) + loss terms.
// One block per (b, h) row; each thread handles 2 columns.
// All finite distance values are exact small ints in fp32.
// ---------------------------------------------------------------------------
__global__ __launch_bounds__(256) void rows_loss_kernel(
    const float* __restrict__ logits, const unsigned int* __restrict__ mask,
    const short* __restrict__ un_s, const short* __restrict__ dn_s,
    float* __restrict__ partials) {
  __shared__ float s[PADK + WW + PADK];
  __shared__ float wsum[4][4];

  int row = blockIdx.x;             // b*HH + h
  int b = row >> 9, i = row & 511;  // h index within image
  size_t rowbase = (size_t)row * WW;
  int tid = threadIdx.x;

  // pads (never allowed to win the min)
  s[tid] = 3e12f; s[tid + 256] = 3e12f;
  s[PADK + WW + tid] = 3e12f; s[PADK + WW + 256 + tid] = 3e12f;

  int k0 = i >> 5, pos = i & 31;    // block-uniform
  unsigned int pmask_lo = (1u << pos) - 1u;       // bits < pos
  unsigned int pmask_le = pmask_lo | (1u << pos); // bits <= pos
  const unsigned int* mrow = mask + (size_t)(b * NWORDS + k0) * WW;
  const short* unrow = un_s + (size_t)(b * 17 + k0 + 1) * WW;  // first set >= 32(k0+1)
  const short* dnrow = dn_s + (size_t)(b * 17 + k0) * WW;      // last set <= 32(k0-1)+31
  float tval[2];

  #pragma unroll
  for (int k2 = 0; k2 < 2; ++k2) {
    int w = tid + (k2 << 8);
    unsigned int m0 = mrow[w];
    int un_next = unrow[w];
    int dn_prev = dnrow[w];
    unsigned int upm  = m0 & ~pmask_lo;   // bits >= pos
    unsigned int lowm = m0 & pmask_le;    // bits <= pos
    int up  = upm  ? ((k0 << 5) + (int)__builtin_ctz(upm))        : un_next;
    int dnv = lowm ? ((k0 << 5) + 31 - (int)__builtin_clz(lowm))  : dn_prev;
    int bestv = min(up - i, i - dnv);
    tval[k2] = (up == i) ? 1.f : 0.f;     // bit i set iff nearest-up is i itself
    s[PADK + w] = (bestv > 511) ? 1e12f : (float)(bestv * bestv);
  }
  __syncthreads();

  float acc_p = 0.f, acc_t = 0.f, acc_pt = 0.f, acc_pen = 0.f;

  #pragma unroll
  for (int k2 = 0; k2 < 2; ++k2) {
    int w = tid + (k2 << 8);
    float x = logits[rowbase + w];     // issue early, consumed after scan
    float best = s[PADK + w];
    for (int o0 = 1; o0 < WW; o0 += 8) {
      if (__all((float)(o0 * o0) >= best)) break;  // wave-uniform exit
      #pragma unroll
      for (int u = 0; u < 8; ++u) {
        int o = o0 + u;
        float cand = fminf(s[PADK + w - o], s[PADK + w + o]) + (float)(o * o);
        best = fminf(best, cand);      // unconditional: losers can't lower best
      }
    }
    float e = __expf(-x);
    float p = __builtin_amdgcn_rcpf(1.f + e);          // sigmoid, ~1e-7 rel err
    float t = tval[k2];
    // empty sample => best ~ 1e12 => reference forces weight 0 (has_fg)
    float wgt = (best > 1e9f)
                    ? 0.f
                    : (1.f - __expf(-__builtin_amdgcn_sqrtf(best) * 0.02f));
    acc_p  += p;
    acc_t  += t;
    acc_pt += p * t;
    acc_pen += wgt * p * (1.f - t);
  }

  // wave(64) shuffle reduce, then across the 4 waves via LDS
  #pragma unroll
  for (int off = 32; off; off >>= 1) {
    acc_p  += __shfl_down(acc_p,  off);
    acc_t  += __shfl_down(acc_t,  off);
    acc_pt += __shfl_down(acc_pt, off);
    acc_pen += __shfl_down(acc_pen, off);
  }
  int wave = tid >> 6, lane = tid & 63;
  if (lane == 0) {
    wsum[wave][0] = acc_p; wsum[wave][1] = acc_t;
    wsum[wave][2] = acc_pt; wsum[wave][3] = acc_pen;
  }
  __syncthreads();
  if (tid == 0) {
    float r0 = 0.f, r1 = 0.f, r2 = 0.f, r3 = 0.f;
    #pragma unroll
    for (int wv = 0; wv < 4; ++wv) {
      r0 += wsum[wv][0]; r1 += wsum[wv][1];
      r2 += wsum[wv][2]; r3 += wsum[wv][3];
    }
    partials[0 * NROWS + row] = r0;
    partials[1 * NROWS + row] = r1;
    partials[2 * NROWS + row] = r2;
    partials[3 * NROWS + row] = r3;
  }
}

// ---------------------------------------------------------------------------
// Kernel C: deterministic final reduce of 8192x4 partials + scalar loss.
// ---------------------------------------------------------------------------
__global__ __launch_bounds__(256) void finalize_kernel(
    const float* __restrict__ partials, float* __restrict__ out) {
  __shared__ float wsum[4][4];
  int tid = threadIdx.x;
  float a0 = 0.f, a1 = 0.f, a2 = 0.f, a3 = 0.f;
  for (int k = tid; k < NROWS; k += 256) {
    a0 += partials[0 * NROWS + k];
    a1 += partials[1 * NROWS + k];
    a2 += partials[2 * NROWS + k];
    a3 += partials[3 * NROWS + k];
  }
  #pragma unroll
  for (int off = 32; off; off >>= 1) {
    a0 += __shfl_down(a0, off);
    a1 += __shfl_down(a1, off);
    a2 += __shfl_down(a2, off);
    a3 += __shfl_down(a3, off);
  }
  int wave = tid >> 6, lane = tid & 63;
  if (lane == 0) {
    wsum[wave][0] = a0; wsum[wave][1] = a1;
    wsum[wave][2] = a2; wsum[wave][3] = a3;
  }
  __syncthreads();
  if (tid == 0) {
    float sp = 0.f, st = 0.f, inter = 0.f, pen = 0.f;
    #pragma unroll
    for (int wv = 0; wv < 4; ++wv) {
      sp += wsum[wv][0]; st += wsum[wv][1];
      inter += wsum[wv][2]; pen += wsum[wv][3];
    }
    float uni = sp + st - inter;
    float iou_loss = 1.f - (inter + 1e-6f) / (uni + 1e-6f);
    float penalty = pen / (float)NPIX;
    out[0] = iou_loss + 0.5f * penalty;
  }
}

extern "C" void kernel_launch(void* const* d_in, const int* in_sizes, int n_in,
                              void* d_out, int out_size, void* d_ws, size_t ws_size,
                              hipStream_t stream) {
  const float* logits = (const float*)d_in[0];
  const float* tg     = (const float*)d_in[1];
  char* base = (char*)d_ws;
  unsigned int* mask = (unsigned int*)base;            // 512 KB
  short* un_s = (short*)(base + 524288);               // 16*17*512 shorts = 272 KB
  short* dn_s = (short*)(base + 802816);               // 272 KB
  float* partials = (float*)(base + 1081344);          // 128 KB
  float* out = (float*)d_out;

  hipLaunchKernelGGL(build_kernel, dim3(BB * 8), dim3(256), 0, stream,
                     tg, mask, un_s, dn_s);
  hipLaunchKernelGGL(rows_loss_kernel, dim3(NROWS), dim3(256), 0, stream,
                     logits, mask, un_s, dn_s, partials);
  hipLaunchKernelGGL(finalize_kernel, dim3(1), dim3(256), 0, stream,
                     partials, out);
}